// Round 5
// baseline (346.970 us; speedup 1.0000x reference)
//
#include <hip/hip_runtime.h>
#include <hip/hip_bf16.h>

#define N_NODES 100000
#define N_EDGES 1600000
#define HDIM    128
#define KCH     4                  // K chunks of 32 (K = 128)
#define NUM_CARDS 110
#define NTILES  (N_NODES / 16)     // 6250 exactly
#define GEMM_BLOCKS 1024

#define NB      196                // node buckets: dst >> 9
#define MAXB    10240              // slack per bucket (avg 8192)
#define PT      4096               // edges per partition block
#define PEPT    16                 // edges per thread in partition

typedef __attribute__((ext_vector_type(8))) short bfrag;   // 8 bf16 = 4 VGPRs
typedef __attribute__((ext_vector_type(4))) float ffrag;   // 4 f32 acc
typedef __attribute__((ext_vector_type(2))) float f32x2;

__device__ inline unsigned short f2bf(float f) {
    __hip_bfloat16 h = __float2bfloat16(f);
    unsigned short u; __builtin_memcpy(&u, &h, 2); return u;
}

// async global->LDS, 16B per lane; LDS dest = wave-uniform base + lane*16
__device__ inline void gload_lds16(const void* g, void* l) {
    __builtin_amdgcn_global_load_lds(
        (const __attribute__((address_space(1))) unsigned int*)g,
        (__attribute__((address_space(3))) unsigned int*)l, 16, 0, 0);
}

// ---------------- CSR build: bucketed counting sort ----------------
// pack: (dst & 511) << 17 | src   (src < 2^17)

__global__ __launch_bounds__(256) void k_partition(
    const int* __restrict__ src, const int* __restrict__ dst,
    int* __restrict__ bucket_cursor, unsigned int* __restrict__ part) {
    __shared__ int hist[NB];
    __shared__ int hcur[NB];
    const int t = threadIdx.x;
    const int base = blockIdx.x * PT;
    for (int i = t; i < NB; i += 256) hist[i] = 0;
    __syncthreads();
#pragma unroll
    for (int i = 0; i < PEPT; i++) {
        int e = base + i * 256 + t;
        if (e < N_EDGES) atomicAdd(&hist[dst[e] >> 9], 1);
    }
    __syncthreads();
    for (int b = t; b < NB; b += 256) {
        int h = hist[b];
        hcur[b] = h ? atomicAdd(&bucket_cursor[b], h) : 0;
    }
    __syncthreads();
#pragma unroll
    for (int i = 0; i < PEPT; i++) {
        int e = base + i * 256 + t;
        if (e < N_EDGES) {
            int d = dst[e];
            int b = d >> 9;
            int r = atomicAdd(&hcur[b], 1);
            if (r < MAXB)
                part[(size_t)b * MAXB + r] =
                    ((unsigned int)(d & 511) << 17) | (unsigned int)src[e];
        }
    }
}

// fixed-stride csr layout: bucket b owns csr_src[b*MAXB .. b*MAXB+cnt)
__global__ __launch_bounds__(256) void k_bucket(
    const unsigned int* __restrict__ part, const int* __restrict__ bucket_cursor,
    int* __restrict__ row_off, int* __restrict__ deg, float* __restrict__ deg_inv,
    int* __restrict__ csr_src) {
    __shared__ int degl[512];
    __shared__ int offl[512];
    __shared__ int curl[512];
    __shared__ int stmp[256];
    const int t = threadIdx.x;
    const int b = blockIdx.x;
    const int n0 = b << 9;
    const int nb = min(512, N_NODES - n0);
    const int cnt = min(bucket_cursor[b], MAXB);
    const int row0 = b * MAXB;
    const unsigned int* pb = &part[(size_t)b * MAXB];

    degl[t] = 0; degl[t + 256] = 0;
    __syncthreads();
    for (int i = t; i < cnt; i += 256)
        atomicAdd(&degl[pb[i] >> 17], 1);
    __syncthreads();
    const int a0 = degl[2 * t], a1 = degl[2 * t + 1];
    stmp[t] = a0 + a1;
    __syncthreads();
    for (int off = 1; off < 256; off <<= 1) {
        int x = (t >= off) ? stmp[t - off] : 0;
        __syncthreads();
        stmp[t] += x;
        __syncthreads();
    }
    const int excl = stmp[t] - (a0 + a1);
    offl[2 * t] = excl;          curl[2 * t] = excl;
    offl[2 * t + 1] = excl + a0; curl[2 * t + 1] = excl + a0;
    __syncthreads();
    for (int i = t; i < nb; i += 256) {
        int n = n0 + i;
        int d = degl[i];
        row_off[n] = row0 + offl[i];
        deg[n] = d;
        deg_inv[n] = (d > 0) ? 1.0f / (float)d : 0.0f;
    }
    for (int i = t; i < cnt; i += 256) {
        unsigned int pk = pb[i];
        int r = atomicAdd(&curl[pk >> 17], 1);
        csr_src[row0 + r] = (int)(pk & 0x1FFFFu);
    }
}

// ---------------- prep: weights -> bf16 concat layouts ----------------

__global__ void k_prep_w(const float* __restrict__ Wl1, const float* __restrict__ Wr1,
                         const float* __restrict__ bl1, const float* __restrict__ br1,
                         const float* __restrict__ Wl2, const float* __restrict__ Wr2,
                         const float* __restrict__ bl2, const float* __restrict__ br2,
                         const float* __restrict__ Wo,  const float* __restrict__ bo,
                         unsigned short* __restrict__ W1, unsigned short* __restrict__ W2,
                         unsigned short* __restrict__ Wob,
                         float* __restrict__ bias1, float* __restrict__ bias2,
                         float* __restrict__ biaso, float* __restrict__ wcard1) {
    const int j = blockIdx.x;   // 0..255
    const int k = threadIdx.x;  // 0..127
    const float* s1 = (j < 128) ? &Wl1[(size_t)j * 129] : &Wr1[(size_t)(j - 128) * 129];
    W1[(size_t)j * HDIM + k] = f2bf(s1[k]);
    const float* s2 = (j < 128) ? &Wl2[(size_t)j * HDIM] : &Wr2[(size_t)(j - 128) * HDIM];
    W2[(size_t)j * HDIM + k] = f2bf(s2[k]);
    if (j < 112)
        Wob[(size_t)j * HDIM + k] = (j < NUM_CARDS) ? f2bf(Wo[(size_t)j * HDIM + k])
                                                    : (unsigned short)0;
    if (k == 0) {
        wcard1[j] = s1[HDIM];
        bias1[j] = (j < 128) ? 0.f : (bl1[j - 128] + br1[j - 128]);
        bias2[j] = (j < 128) ? 0.f : (bl2[j - 128] + br2[j - 128]);
        if (j < 112) biaso[j] = (j < NUM_CARDS) ? bo[j] : 0.f;
    }
}

// ---------------- layer-1 GEMM: x -> Gq (fp8) + Rb (bf16) ----------------
// Triple-buffered LDS staging, counted vmcnt(2) (stage = 2 gload_lds/wave).
// R4: cards pre-staged into LDS in the prologue (<=7 tiles/block) -> the
// per-iteration cv read is a ds_read, fully decoupled from the vmcnt queue
// (the old loop-carried register copy could force a drain of the fresh
// stage). Waves 0,1 produce G units (fp8), waves 2,3 R units (bf16).

__global__ __launch_bounds__(256) void k_gemm1(
    const float* __restrict__ Af, const int* __restrict__ cards,
    const unsigned short* __restrict__ W,
    const float* __restrict__ bias, const float* __restrict__ wcard,
    unsigned char* __restrict__ Gq, unsigned short* __restrict__ Rb) {
    __shared__ __align__(16) unsigned char smem[3 * 8192 + 2048 + 512];
    float* bias_l = (float*)(smem + 3 * 8192);
    float* wc_l   = (float*)(smem + 3 * 8192 + 1024);
    float* cl     = (float*)(smem + 3 * 8192 + 2048);   // 7*16 floats

    const int tix  = threadIdx.x;
    const int wave = tix >> 6;
    const int lane = tix & 63;
    const int m16  = lane & 15;
    const int quad = lane >> 4;
    const int u0   = wave * 4;
    const bool isG = (wave < 2);
    const int xk   = m16 & 7;
    const int bid  = blockIdx.x;

    // weights -> regs (64 VGPR)
    bfrag wf[4][KCH];
#pragma unroll
    for (int u = 0; u < 4; u++) {
        const int j = (u0 + u) * 16 + m16;
#pragma unroll
        for (int c = 0; c < KCH; c++)
            wf[u][c] = *(const bfrag*)&W[(size_t)j * HDIM + c * 32 + quad * 8];
    }

    bias_l[tix] = bias[tix];
    wc_l[tix]   = wcard[tix];
    if (tix < 16) {
#pragma unroll
        for (int i = 0; i < 7; i++) {
            const int t = bid + i * GEMM_BLOCKS;
            if (t < NTILES) cl[i * 16 + tix] = (float)cards[t * 16 + tix];
        }
    }

    // rule #21 staging: linear LDS dest, inverse-swizzled global source,
    // swizzled ds_read. f32 row = 32 chunks of 16B.
    const int sw = (tix ^ ((tix >> 5) & 7)) << 4;
    const int ldsoff = wave << 10;   // wave * 1024 (64 lanes x 16B)

#define STAGE1(T, BI)                                                         \
    do {                                                                      \
        const unsigned char* g_ = (const unsigned char*)Af + (size_t)(T) * 8192; \
        unsigned char* d_ = smem + (BI) * 8192 + ldsoff;                      \
        gload_lds16(g_ + sw, d_);                                             \
        gload_lds16(g_ + sw + 4096, d_ + 4096);                               \
    } while (0)

    int tile = blockIdx.x;
    STAGE1(tile, 0);
    asm volatile("s_waitcnt lgkmcnt(0)" ::: "memory");  // own LDS writes done

    int b = 0, ic = 0;
    for (; tile < NTILES; tile += GEMM_BLOCKS, ic++) {
        const int tn = tile + GEMM_BLOCKS;
        if (tn < NTILES) STAGE1(tn, (b == 2 ? 0 : b + 1));  // stays in flight
        asm volatile("s_waitcnt vmcnt(2)" ::: "memory");    // buf(t) staged
        __builtin_amdgcn_s_barrier();
        __builtin_amdgcn_sched_barrier(0);

        const float cv = cl[ic * 16 + m16];   // ds_read, no vmcnt coupling

        const unsigned char* B = smem + b * 8192;
        bfrag hf[KCH];
#pragma unroll
        for (int c = 0; c < KCH; c++) {
            const int s0 = m16 * 32 + c * 8 + quad * 2;
            const float4 p0 = *(const float4*)(B + (((s0    ) ^ xk) << 4));
            const float4 p1 = *(const float4*)(B + (((s0 + 1) ^ xk) << 4));
            bfrag h;
            h[0] = (short)f2bf(p0.x); h[1] = (short)f2bf(p0.y);
            h[2] = (short)f2bf(p0.z); h[3] = (short)f2bf(p0.w);
            h[4] = (short)f2bf(p1.x); h[5] = (short)f2bf(p1.y);
            h[6] = (short)f2bf(p1.z); h[7] = (short)f2bf(p1.w);
            hf[c] = h;
        }

        const int node = tile * 16 + m16;
#pragma unroll
        for (int u = 0; u < 4; u++) {
            ffrag acc = {0.f, 0.f, 0.f, 0.f};
#pragma unroll
            for (int c = 0; c < KCH; c++)
                acc = __builtin_amdgcn_mfma_f32_16x16x32_bf16(wf[u][c], hf[c], acc, 0, 0, 0);
            const int jj0 = (u0 + u) * 16 + quad * 4;
            const float4 b0 = *(const float4*)&bias_l[jj0];
            const float4 w0 = *(const float4*)&wc_l[jj0];
            float v[4];
            v[0] = acc[0] + b0.x + cv * w0.x;
            v[1] = acc[1] + b0.y + cv * w0.y;
            v[2] = acc[2] + b0.z + cv * w0.z;
            v[3] = acc[3] + b0.w + cv * w0.w;
            if (isG) {
                int pk = __builtin_amdgcn_cvt_pk_fp8_f32(v[0], v[1], 0, false);
                pk = __builtin_amdgcn_cvt_pk_fp8_f32(v[2], v[3], pk, true);
                *(unsigned int*)&Gq[(size_t)node * HDIM + (u0 + u) * 16 + quad * 4] =
                    (unsigned int)pk;
            } else {
                unsigned short o[4];
#pragma unroll
                for (int r = 0; r < 4; r++) o[r] = f2bf(v[r]);
                uint2 p = {(unsigned int)o[0] | ((unsigned int)o[1] << 16),
                           (unsigned int)o[2] | ((unsigned int)o[3] << 16)};
                *(uint2*)&Rb[(size_t)node * HDIM + (u0 + u - 8) * 16 + quad * 4] = p;
            }
        }
        b = (b == 2 ? 0 : b + 1);
    }
#undef STAGE1
}

// ---------------- FUSED aggregate + GEMM ----------------
// R4: k_agg is BW-walled at ~3 TB/s (three configs, same 40 us) with VALU
// 31% and MFMA 0% -> fuse the downstream GEMM into the same kernel so it
// runs in the gather's bandwidth shadow, and the h-tile round-trip through
// global (bufH: 51 MB of traffic) disappears into LDS.
//   Phase A (agg): 8 nodes/wave, 8 lanes/node, lane privately accumulates
//     16 fp8 features (proven R2 structure, 28 VGPR). Result -> LDS h-tile
//     [32][128] bf16 with chunk-XOR swizzle (chunk ^ (row&7)) — verified
//     conflict-free for both the agg write and the GEMM fragment read.
//   Phase B (GEMM): after __syncthreads, weights load (post-barrier,
//     sched-fenced so they don't inflate agg-phase VGPR), then 2 MFMA
//     tiles of 16 nodes.
// MODE 0: dual W2 -> Gq2 (fp8, waves 0,1) + Rb2 (bf16, waves 2,3).
// MODE 1: logits Wo (7 j-units) -> out f32 j-major.

template <int MODE>
__global__ __launch_bounds__(256) void k_agg_gemm(
    const unsigned char* __restrict__ Gq, const unsigned short* __restrict__ Rb,
    const int* __restrict__ row_off, const int* __restrict__ deg,
    const float* __restrict__ deg_inv, const int* __restrict__ csr_src,
    const unsigned short* __restrict__ W, const float* __restrict__ bias,
    unsigned char* __restrict__ Gq2, unsigned short* __restrict__ Rb2,
    float* __restrict__ out) {
    __shared__ __align__(16) unsigned char hlds[32 * 256];   // 8 KB bf16 tile

    const int tix  = threadIdx.x;
    const int wave = tix >> 6;
    const int lane = tix & 63;

    // ---------------- Phase A: aggregate ----------------
    {
        const int g = lane >> 3;        // node slot 0..7 within wave
        const int l = lane & 7;         // feature slice within node
        const int nl = wave * 8 + g;    // node-local 0..31
        const int n = blockIdx.x * 32 + nl;
        const int start = row_off[n];
        const int d = deg[n];
        const float di = deg_inv[n];
        const int fo = l * 16;          // fp8 byte offset == bf16 elem offset

        int dmax = d;
        dmax = max(dmax, __shfl_xor(dmax, 8, 64));
        dmax = max(dmax, __shfl_xor(dmax, 16, 64));
        dmax = max(dmax, __shfl_xor(dmax, 32, 64));

        // R slice (self term), all 64 lanes useful
        const uint4 rv0 = *(const uint4*)&Rb[(size_t)n * HDIM + fo];
        const uint4 rv1 = *(const uint4*)&Rb[(size_t)n * HDIM + fo + 8];

        f32x2 acc2[8];
#pragma unroll
        for (int i = 0; i < 8; i++) acc2[i] = (f32x2){0.f, 0.f};

        int idxA = (l < d) ? csr_src[start + l] * HDIM : 0;
        int idxB = (8 + l < d) ? csr_src[start + 8 + l] * HDIM : 0;

        uint4 cur = {0u, 0u, 0u, 0u};
        {
            const int off0 = __shfl(idxA, g << 3, 64);     // full-exec shfl
            if (0 < d) cur = *(const uint4*)&Gq[(size_t)(unsigned)off0 + fo];
        }
#define ACC16(Cv)                                                        \
    acc2[0] += __builtin_amdgcn_cvt_pk_f32_fp8((int)(Cv).x, false);      \
    acc2[1] += __builtin_amdgcn_cvt_pk_f32_fp8((int)(Cv).x, true);       \
    acc2[2] += __builtin_amdgcn_cvt_pk_f32_fp8((int)(Cv).y, false);      \
    acc2[3] += __builtin_amdgcn_cvt_pk_f32_fp8((int)(Cv).y, true);       \
    acc2[4] += __builtin_amdgcn_cvt_pk_f32_fp8((int)(Cv).z, false);      \
    acc2[5] += __builtin_amdgcn_cvt_pk_f32_fp8((int)(Cv).z, true);       \
    acc2[6] += __builtin_amdgcn_cvt_pk_f32_fp8((int)(Cv).w, false);      \
    acc2[7] += __builtin_amdgcn_cvt_pk_f32_fp8((int)(Cv).w, true);

        for (int i = 1; i < dmax; i++) {
            const int sl = i & 7;
            if (sl == 0) {               // wave-uniform chunk rotation
                idxA = idxB;
                const int j = i + 8 + l;
                idxB = (j < d) ? csr_src[start + j] * HDIM : 0;
            }
            const int offn = __shfl(idxA, (g << 3) | sl, 64);
            uint4 nxt = {0u, 0u, 0u, 0u};
            if (i < d) nxt = *(const uint4*)&Gq[(size_t)(unsigned)offn + fo];
            ACC16(cur);                  // vmcnt(1): nxt stays in flight
            cur = nxt;
        }
        ACC16(cur);
#undef ACC16

        // relu(mean + R) -> bf16 -> LDS (chunk-XOR swizzle, key = nl&7 = g)
        const unsigned int ru[8] = {rv0.x, rv0.y, rv0.z, rv0.w,
                                    rv1.x, rv1.y, rv1.z, rv1.w};
        unsigned short o[16];
#pragma unroll
        for (int i = 0; i < 8; i++) {
            unsigned int lo_ = ru[i] << 16, hi_ = ru[i] & 0xffff0000u;
            float rl, rh;
            __builtin_memcpy(&rl, &lo_, 4); __builtin_memcpy(&rh, &hi_, 4);
            o[2 * i]     = f2bf(fmaxf(acc2[i].x * di + rl, 0.f));
            o[2 * i + 1] = f2bf(fmaxf(acc2[i].y * di + rh, 0.f));
        }
        uint4 p0, p1;
        p0.x = (unsigned int)o[0] | ((unsigned int)o[1] << 16);
        p0.y = (unsigned int)o[2] | ((unsigned int)o[3] << 16);
        p0.z = (unsigned int)o[4] | ((unsigned int)o[5] << 16);
        p0.w = (unsigned int)o[6] | ((unsigned int)o[7] << 16);
        p1.x = (unsigned int)o[8] | ((unsigned int)o[9] << 16);
        p1.y = (unsigned int)o[10] | ((unsigned int)o[11] << 16);
        p1.z = (unsigned int)o[12] | ((unsigned int)o[13] << 16);
        p1.w = (unsigned int)o[14] | ((unsigned int)o[15] << 16);
        *(uint4*)(hlds + nl * 256 + (((l * 2    ) ^ g) << 4)) = p0;
        *(uint4*)(hlds + nl * 256 + (((l * 2 + 1) ^ g) << 4)) = p1;
    }
    __syncthreads();
    __builtin_amdgcn_sched_barrier(0);   // keep weight loads post-barrier

    // ---------------- Phase B: GEMM from LDS ----------------
    const int m16  = lane & 15;
    const int quad = lane >> 4;
    const int xk   = m16 & 7;

    // fragments for both 16-node tiles (swizzled LDS read)
    bfrag hf[2][KCH];
#pragma unroll
    for (int T = 0; T < 2; T++)
#pragma unroll
        for (int c = 0; c < KCH; c++) {
            const int chunk = (c * 4 + quad) ^ xk;
            hf[T][c] = *(const bfrag*)(hlds + (T * 16 + m16) * 256 + (chunk << 4));
        }

    if (MODE == 0) {
        const int u0 = wave * 4;
        const bool isG = (wave < 2);
        bfrag wf[4][KCH];
#pragma unroll
        for (int u = 0; u < 4; u++) {
            const int j = (u0 + u) * 16 + m16;
#pragma unroll
            for (int c = 0; c < KCH; c++)
                wf[u][c] = *(const bfrag*)&W[(size_t)j * HDIM + c * 32 + quad * 8];
        }
#pragma unroll
        for (int T = 0; T < 2; T++) {
            const int node = blockIdx.x * 32 + T * 16 + m16;
#pragma unroll
            for (int u = 0; u < 4; u++) {
                ffrag acc = {0.f, 0.f, 0.f, 0.f};
#pragma unroll
                for (int c = 0; c < KCH; c++)
                    acc = __builtin_amdgcn_mfma_f32_16x16x32_bf16(wf[u][c], hf[T][c], acc, 0, 0, 0);
                const int jj0 = (u0 + u) * 16 + quad * 4;
                const float4 b0 = *(const float4*)&bias[jj0];
                float v[4] = {acc[0] + b0.x, acc[1] + b0.y,
                              acc[2] + b0.z, acc[3] + b0.w};
                if (isG) {
                    int pk = __builtin_amdgcn_cvt_pk_fp8_f32(v[0], v[1], 0, false);
                    pk = __builtin_amdgcn_cvt_pk_fp8_f32(v[2], v[3], pk, true);
                    *(unsigned int*)&Gq2[(size_t)node * HDIM + (u0 + u) * 16 + quad * 4] =
                        (unsigned int)pk;
                } else {
                    unsigned short oo[4];
#pragma unroll
                    for (int r = 0; r < 4; r++) oo[r] = f2bf(v[r]);
                    uint2 p = {(unsigned int)oo[0] | ((unsigned int)oo[1] << 16),
                               (unsigned int)oo[2] | ((unsigned int)oo[3] << 16)};
                    *(uint2*)&Rb2[(size_t)node * HDIM + (u0 + u - 8) * 16 + quad * 4] = p;
                }
            }
        }
    } else {
        const int u0 = wave * 2;
        bfrag wf[2][KCH];
        float bsj[2];
#pragma unroll
        for (int u = 0; u < 2; u++) {
            const int unit = u0 + u;
            const int j = (unit < 7 ? unit : 0) * 16 + m16;
#pragma unroll
            for (int c = 0; c < KCH; c++)
                wf[u][c] = *(const bfrag*)&W[(size_t)j * HDIM + c * 32 + quad * 8];
            bsj[u] = bias[j];
        }
#pragma unroll
        for (int T = 0; T < 2; T++) {
#pragma unroll
            for (int u = 0; u < 2; u++) {
                const int unit = u0 + u;
                if (unit >= 7) break;
                ffrag acc = {0.f, 0.f, 0.f, 0.f};
#pragma unroll
                for (int c = 0; c < KCH; c++)
                    acc = __builtin_amdgcn_mfma_f32_16x16x32_bf16(hf[T][c], wf[u][c], acc, 0, 0, 0);
                const int j = unit * 16 + m16;
                if (j < NUM_CARDS) {
#pragma unroll
                    for (int r = 0; r < 4; r++) {
                        const int node = blockIdx.x * 32 + T * 16 + quad * 4 + r;
                        out[(size_t)node * NUM_CARDS + j] = acc[r] + bsj[u];
                    }
                }
            }
        }
    }
}

// ---------------- launch ----------------

static inline size_t align_up(size_t x, size_t a) { return (x + a - 1) & ~(a - 1); }

extern "C" void kernel_launch(void* const* d_in, const int* in_sizes, int n_in,
                              void* d_out, int out_size, void* d_ws, size_t ws_size,
                              hipStream_t stream) {
    const float* x   = (const float*)d_in[0];
    const float* Wl1 = (const float*)d_in[1];
    const float* bl1 = (const float*)d_in[2];
    const float* Wr1 = (const float*)d_in[3];
    const float* br1 = (const float*)d_in[4];
    const float* Wl2 = (const float*)d_in[5];
    const float* bl2 = (const float*)d_in[6];
    const float* Wr2 = (const float*)d_in[7];
    const float* br2 = (const float*)d_in[8];
    const float* Wo  = (const float*)d_in[9];
    const float* bo  = (const float*)d_in[10];
    const int* edge  = (const int*)d_in[11];
    const int* cards = (const int*)d_in[12];
    float* logits = (float*)d_out;

    const int* e_src = edge;
    const int* e_dst = edge + N_EDGES;

    char* w = (char*)d_ws;
    size_t off = 0;
    int* bucket_cursor = (int*)(w + off); off = align_up(off + 256 * 4, 512);
    unsigned int* part = (unsigned int*)(w + off); off = align_up(off + (size_t)NB * MAXB * 4, 512);
    int* row_off = (int*)(w + off); off = align_up(off + N_NODES * 4, 512);
    int* deg_i   = (int*)(w + off); off = align_up(off + N_NODES * 4, 512);
    float* dinv  = (float*)(w + off); off = align_up(off + N_NODES * 4, 512);
    int* csr_src = (int*)(w + off); off = align_up(off + (size_t)NB * MAXB * 4, 512);
    unsigned char*  Gq   = (unsigned char*)(w + off);  off = align_up(off + (size_t)N_NODES * HDIM, 512);
    unsigned short* Rb   = (unsigned short*)(w + off); off = align_up(off + (size_t)N_NODES * HDIM * 2, 512);
    unsigned char*  Gq2  = (unsigned char*)(w + off);  off = align_up(off + (size_t)N_NODES * HDIM, 512);
    unsigned short* Rb2  = (unsigned short*)(w + off); off = align_up(off + (size_t)N_NODES * HDIM * 2, 512);
    unsigned short* W1   = (unsigned short*)(w + off); off = align_up(off + 256 * HDIM * 2, 512);
    unsigned short* W2   = (unsigned short*)(w + off); off = align_up(off + 256 * HDIM * 2, 512);
    unsigned short* Wob  = (unsigned short*)(w + off); off = align_up(off + 112 * HDIM * 2, 512);
    float* bias1  = (float*)(w + off); off = align_up(off + 256 * 4, 512);
    float* bias2  = (float*)(w + off); off = align_up(off + 256 * 4, 512);
    float* biaso  = (float*)(w + off); off = align_up(off + 112 * 4, 512);
    float* wcard1 = (float*)(w + off); off = align_up(off + 256 * 4, 512);
    (void)ws_size; (void)n_in; (void)in_sizes; (void)out_size;

    hipMemsetAsync(bucket_cursor, 0, 256 * 4, stream);
    k_prep_w<<<256, 128, 0, stream>>>(Wl1, Wr1, bl1, br1, Wl2, Wr2, bl2, br2, Wo, bo,
                                      W1, W2, Wob, bias1, bias2, biaso, wcard1);

    const int PBLK = (N_EDGES + PT - 1) / PT;   // 391
    k_partition<<<PBLK, 256, 0, stream>>>(e_src, e_dst, bucket_cursor, part);
    k_bucket<<<NB, 256, 0, stream>>>(part, bucket_cursor,
                                     row_off, deg_i, dinv, csr_src);

    // layer 1 GEMM (x f32 -> Gq fp8 + Rb bf16)
    k_gemm1<<<GEMM_BLOCKS, 256, 0, stream>>>(x, cards, W1, bias1, wcard1, Gq, Rb);
    // fused: agg(layer1) + GEMM(W2) -> Gq2/Rb2
    k_agg_gemm<0><<<N_NODES / 32, 256, 0, stream>>>(
        Gq, Rb, row_off, deg_i, dinv, csr_src, W2, bias2, Gq2, Rb2, nullptr);
    // fused: agg(layer2) + logits GEMM -> out
    k_agg_gemm<1><<<N_NODES / 32, 256, 0, stream>>>(
        Gq2, Rb2, row_off, deg_i, dinv, csr_src, Wob, biaso, nullptr, nullptr, logits);
}

// Round 6
// 310.987 us; speedup vs baseline: 1.1157x; 1.1157x over previous
//
#include <hip/hip_runtime.h>
#include <hip/hip_bf16.h>

#define N_NODES 100000
#define N_EDGES 1600000
#define HDIM    128
#define KCH     4                  // K chunks of 32 (K = 128)
#define NUM_CARDS 110
#define NTILES  (N_NODES / 16)     // 6250 exactly
#define GB1     1024               // gemm1 blocks per half
#define HALF1   3125               // gemm1 tiles per half
#define GB2     2048               // gemm2/logits grid

#define NB      196                // node buckets: dst >> 9
#define MAXB    10240              // slack per bucket (avg 8192)
#define PT      4096               // edges per partition block
#define PEPT    16                 // edges per thread in partition
#define PBLK    ((N_EDGES + PT - 1) / PT)   // 391

typedef __attribute__((ext_vector_type(8))) short bfrag;   // 8 bf16 = 4 VGPRs
typedef __attribute__((ext_vector_type(4))) float ffrag;   // 4 f32 acc
typedef __attribute__((ext_vector_type(2))) float f32x2;

typedef __attribute__((ext_vector_type(2))) unsigned int uint2v;

__device__ inline unsigned short f2bf(float f) {
    __hip_bfloat16 h = __float2bfloat16(f);
    unsigned short u; __builtin_memcpy(&u, &h, 2); return u;
}
__device__ inline float bf_lo(unsigned int u) {
    unsigned int v = u << 16; float f; __builtin_memcpy(&f, &v, 4); return f;
}
__device__ inline float bf_hi(unsigned int u) {
    unsigned int v = u & 0xffff0000u; float f; __builtin_memcpy(&f, &v, 4); return f;
}

// async global->LDS, 16B per lane; LDS dest = wave-uniform base + lane*16
__device__ inline void gload_lds16(const void* g, void* l) {
    __builtin_amdgcn_global_load_lds(
        (const __attribute__((address_space(1))) unsigned int*)g,
        (__attribute__((address_space(3))) unsigned int*)l, 16, 0, 0);
}

// LDS budget for the merged kernels = gemm1 requirement (covers CSR paths)
#define SMEM1_SZ (3 * 8192 + 2048 + 256)

// ---------------- CSR build bodies (LDS aliased into smem) ----------------
// pack: (dst & 511) << 17 | src   (src < 2^17)

__device__ void partition_body(
    int bid, const int* __restrict__ src, const int* __restrict__ dst,
    int* __restrict__ bucket_cursor, unsigned int* __restrict__ part,
    unsigned char* smem) {
    int* hist = (int*)smem;          // NB ints
    int* hcur = hist + NB;           // NB ints
    const int t = threadIdx.x;
    const int base = bid * PT;
    for (int i = t; i < NB; i += 256) hist[i] = 0;
    __syncthreads();
#pragma unroll
    for (int i = 0; i < PEPT; i++) {
        int e = base + i * 256 + t;
        if (e < N_EDGES) atomicAdd(&hist[dst[e] >> 9], 1);
    }
    __syncthreads();
    for (int b = t; b < NB; b += 256) {
        int h = hist[b];
        hcur[b] = h ? atomicAdd(&bucket_cursor[b], h) : 0;
    }
    __syncthreads();
#pragma unroll
    for (int i = 0; i < PEPT; i++) {
        int e = base + i * 256 + t;
        if (e < N_EDGES) {
            int d = dst[e];
            int b = d >> 9;
            int r = atomicAdd(&hcur[b], 1);
            if (r < MAXB)
                part[(size_t)b * MAXB + r] =
                    ((unsigned int)(d & 511) << 17) | (unsigned int)src[e];
        }
    }
}

__device__ void bucket_body(
    int bid, const unsigned int* __restrict__ part,
    const int* __restrict__ bucket_cursor,
    int* __restrict__ row_off, int* __restrict__ deg, float* __restrict__ deg_inv,
    int* __restrict__ csr_src, unsigned char* smem) {
    int* degl = (int*)smem;          // 512
    int* offl = degl + 512;          // 512
    int* curl = offl + 512;          // 512
    int* stmp = curl + 512;          // 256
    const int t = threadIdx.x;
    const int b = bid;
    const int n0 = b << 9;
    const int nb = min(512, N_NODES - n0);
    const int cnt = min(bucket_cursor[b], MAXB);
    const int row0 = b * MAXB;
    const unsigned int* pb = &part[(size_t)b * MAXB];

    degl[t] = 0; degl[t + 256] = 0;
    __syncthreads();
    for (int i = t; i < cnt; i += 256)
        atomicAdd(&degl[pb[i] >> 17], 1);
    __syncthreads();
    const int a0 = degl[2 * t], a1 = degl[2 * t + 1];
    stmp[t] = a0 + a1;
    __syncthreads();
    for (int off = 1; off < 256; off <<= 1) {
        int x = (t >= off) ? stmp[t - off] : 0;
        __syncthreads();
        stmp[t] += x;
        __syncthreads();
    }
    const int excl = stmp[t] - (a0 + a1);
    offl[2 * t] = excl;          curl[2 * t] = excl;
    offl[2 * t + 1] = excl + a0; curl[2 * t + 1] = excl + a0;
    __syncthreads();
    for (int i = t; i < nb; i += 256) {
        int n = n0 + i;
        int d = degl[i];
        row_off[n] = row0 + offl[i];
        deg[n] = d;
        deg_inv[n] = (d > 0) ? 1.0f / (float)d : 0.0f;
    }
    for (int i = t; i < cnt; i += 256) {
        unsigned int pk = pb[i];
        int r = atomicAdd(&curl[pk >> 17], 1);
        csr_src[row0 + r] = (int)(pk & 0x1FFFFu);
    }
}

// ---------------- layer-1 GEMM body: x -> Gq (fp8) + Rb (bf16) ----------------
// Triple-buffered LDS staging, counted vmcnt(2). cards pre-staged into LDS.
// Waves 0,1 produce G units (fp8), waves 2,3 R units (bf16).

__device__ void gemm1_body(
    int bid, int t0, int tend,
    const float* __restrict__ Af, const int* __restrict__ cards,
    const unsigned short* __restrict__ W,
    const float* __restrict__ bias, const float* __restrict__ wcard,
    unsigned char* __restrict__ Gq, unsigned short* __restrict__ Rb,
    unsigned char* smem) {
    float* bias_l = (float*)(smem + 3 * 8192);
    float* wc_l   = (float*)(smem + 3 * 8192 + 1024);
    float* cl     = (float*)(smem + 3 * 8192 + 2048);   // 4*16 floats

    const int tix  = threadIdx.x;
    const int wave = tix >> 6;
    const int lane = tix & 63;
    const int m16  = lane & 15;
    const int quad = lane >> 4;
    const int u0   = wave * 4;
    const bool isG = (wave < 2);
    const int xk   = m16 & 7;

    // weights -> regs (64 VGPR)
    bfrag wf[4][KCH];
#pragma unroll
    for (int u = 0; u < 4; u++) {
        const int j = (u0 + u) * 16 + m16;
#pragma unroll
        for (int c = 0; c < KCH; c++)
            wf[u][c] = *(const bfrag*)&W[(size_t)j * HDIM + c * 32 + quad * 8];
    }

    bias_l[tix] = bias[tix];
    wc_l[tix]   = wcard[tix];
    if (tix < 16) {
#pragma unroll
        for (int i = 0; i < 4; i++) {
            const int t = t0 + bid + i * GB1;
            if (t < tend) cl[i * 16 + tix] = (float)cards[t * 16 + tix];
        }
    }

    // rule #21 staging: linear LDS dest, inverse-swizzled global source,
    // swizzled ds_read. f32 row = 32 chunks of 16B.
    const int sw = (tix ^ ((tix >> 5) & 7)) << 4;
    const int ldsoff = wave << 10;   // wave * 1024 (64 lanes x 16B)

#define STAGE1(T, BI)                                                         \
    do {                                                                      \
        const unsigned char* g_ = (const unsigned char*)Af + (size_t)(T) * 8192; \
        unsigned char* d_ = smem + (BI) * 8192 + ldsoff;                      \
        gload_lds16(g_ + sw, d_);                                             \
        gload_lds16(g_ + sw + 4096, d_ + 4096);                               \
    } while (0)

    int tile = t0 + bid;
    STAGE1(tile, 0);
    asm volatile("s_waitcnt lgkmcnt(0)" ::: "memory");  // own LDS writes done

    int b = 0, ic = 0;
    for (; tile < tend; tile += GB1, ic++) {
        const int tn = tile + GB1;
        if (tn < tend) STAGE1(tn, (b == 2 ? 0 : b + 1));  // stays in flight
        asm volatile("s_waitcnt vmcnt(2)" ::: "memory");  // buf(t) staged
        __builtin_amdgcn_s_barrier();
        __builtin_amdgcn_sched_barrier(0);

        const float cv = cl[ic * 16 + m16];   // ds_read, no vmcnt coupling

        const unsigned char* B = smem + b * 8192;
        bfrag hf[KCH];
#pragma unroll
        for (int c = 0; c < KCH; c++) {
            const int s0 = m16 * 32 + c * 8 + quad * 2;
            const float4 p0 = *(const float4*)(B + (((s0    ) ^ xk) << 4));
            const float4 p1 = *(const float4*)(B + (((s0 + 1) ^ xk) << 4));
            bfrag h;
            h[0] = (short)f2bf(p0.x); h[1] = (short)f2bf(p0.y);
            h[2] = (short)f2bf(p0.z); h[3] = (short)f2bf(p0.w);
            h[4] = (short)f2bf(p1.x); h[5] = (short)f2bf(p1.y);
            h[6] = (short)f2bf(p1.z); h[7] = (short)f2bf(p1.w);
            hf[c] = h;
        }

        const int node = tile * 16 + m16;
#pragma unroll
        for (int u = 0; u < 4; u++) {
            ffrag acc = {0.f, 0.f, 0.f, 0.f};
#pragma unroll
            for (int c = 0; c < KCH; c++)
                acc = __builtin_amdgcn_mfma_f32_16x16x32_bf16(wf[u][c], hf[c], acc, 0, 0, 0);
            const int jj0 = (u0 + u) * 16 + quad * 4;
            const float4 b0 = *(const float4*)&bias_l[jj0];
            const float4 w0 = *(const float4*)&wc_l[jj0];
            float v[4];
            v[0] = acc[0] + b0.x + cv * w0.x;
            v[1] = acc[1] + b0.y + cv * w0.y;
            v[2] = acc[2] + b0.z + cv * w0.z;
            v[3] = acc[3] + b0.w + cv * w0.w;
            if (isG) {
                int pk = __builtin_amdgcn_cvt_pk_fp8_f32(v[0], v[1], 0, false);
                pk = __builtin_amdgcn_cvt_pk_fp8_f32(v[2], v[3], pk, true);
                *(unsigned int*)&Gq[(size_t)node * HDIM + (u0 + u) * 16 + quad * 4] =
                    (unsigned int)pk;
            } else {
                unsigned short o[4];
#pragma unroll
                for (int r = 0; r < 4; r++) o[r] = f2bf(v[r]);
                uint2 p = {(unsigned int)o[0] | ((unsigned int)o[1] << 16),
                           (unsigned int)o[2] | ((unsigned int)o[3] << 16)};
                *(uint2*)&Rb[(size_t)node * HDIM + (u0 + u - 8) * 16 + quad * 4] = p;
            }
        }
        b = (b == 2 ? 0 : b + 1);
    }
#undef STAGE1
}

// ---------------- merged dispatchers: CSR build runs under gemm1 ----------
// K1: partition (391 blocks) || gemm1 tiles [0, 3125)   (1024 blocks)
// K2: bucket    (196 blocks) || gemm1 tiles [3125,6250) (1024 blocks)
// Kernel-boundary ordering preserves partition -> bucket -> agg.

__global__ __launch_bounds__(256) void k_part_gemm1(
    const int* __restrict__ e_src, const int* __restrict__ e_dst,
    int* __restrict__ bucket_cursor, unsigned int* __restrict__ part,
    const float* __restrict__ Af, const int* __restrict__ cards,
    const unsigned short* __restrict__ W,
    const float* __restrict__ bias, const float* __restrict__ wcard,
    unsigned char* __restrict__ Gq, unsigned short* __restrict__ Rb) {
    __shared__ __align__(16) unsigned char smem[SMEM1_SZ];
    if (blockIdx.x < PBLK)
        partition_body(blockIdx.x, e_src, e_dst, bucket_cursor, part, smem);
    else
        gemm1_body(blockIdx.x - PBLK, 0, HALF1, Af, cards, W, bias, wcard,
                   Gq, Rb, smem);
}

__global__ __launch_bounds__(256) void k_bucket_gemm1(
    const unsigned int* __restrict__ part, const int* __restrict__ bucket_cursor,
    int* __restrict__ row_off, int* __restrict__ deg, float* __restrict__ deg_inv,
    int* __restrict__ csr_src,
    const float* __restrict__ Af, const int* __restrict__ cards,
    const unsigned short* __restrict__ W,
    const float* __restrict__ bias, const float* __restrict__ wcard,
    unsigned char* __restrict__ Gq, unsigned short* __restrict__ Rb) {
    __shared__ __align__(16) unsigned char smem[SMEM1_SZ];
    if (blockIdx.x < NB)
        bucket_body(blockIdx.x, part, bucket_cursor, row_off, deg, deg_inv,
                    csr_src, smem);
    else
        gemm1_body(blockIdx.x - NB, HALF1, NTILES, Af, cards, W, bias, wcard,
                   Gq, Rb, smem);
}

// ---------------- prep: weights -> bf16 concat layouts ----------------

__global__ void k_prep_w(const float* __restrict__ Wl1, const float* __restrict__ Wr1,
                         const float* __restrict__ bl1, const float* __restrict__ br1,
                         const float* __restrict__ Wl2, const float* __restrict__ Wr2,
                         const float* __restrict__ bl2, const float* __restrict__ br2,
                         const float* __restrict__ Wo,  const float* __restrict__ bo,
                         unsigned short* __restrict__ W1, unsigned short* __restrict__ W2,
                         unsigned short* __restrict__ Wob,
                         float* __restrict__ bias1, float* __restrict__ bias2,
                         float* __restrict__ biaso, float* __restrict__ wcard1) {
    const int j = blockIdx.x;   // 0..255
    const int k = threadIdx.x;  // 0..127
    const float* s1 = (j < 128) ? &Wl1[(size_t)j * 129] : &Wr1[(size_t)(j - 128) * 129];
    W1[(size_t)j * HDIM + k] = f2bf(s1[k]);
    const float* s2 = (j < 128) ? &Wl2[(size_t)j * HDIM] : &Wr2[(size_t)(j - 128) * HDIM];
    W2[(size_t)j * HDIM + k] = f2bf(s2[k]);
    if (j < 112)
        Wob[(size_t)j * HDIM + k] = (j < NUM_CARDS) ? f2bf(Wo[(size_t)j * HDIM + k])
                                                    : (unsigned short)0;
    if (k == 0) {
        wcard1[j] = s1[HDIM];
        bias1[j] = (j < 128) ? 0.f : (bl1[j - 128] + br1[j - 128]);
        bias2[j] = (j < 128) ? 0.f : (bl2[j - 128] + br2[j - 128]);
        if (j < 112) biaso[j] = (j < NUM_CARDS) ? bo[j] : 0.f;
    }
}

// ---------------- aggregate: h' = relu(mean(Gq[src]) + Rb) ----------------
// R2-proven structure (40.6 us, BW wall): 8 nodes/wave, 8 lanes/node, lane
// privately accumulates 16 fp8 features. No block barrier anywhere (R4
// lesson: barriers downstream of variable-length gathers drain the CU's
// outstanding-request pool and halve gather BW).

__global__ __launch_bounds__(256) void k_agg(
    const unsigned char* __restrict__ Gq, const unsigned short* __restrict__ Rb,
    const int* __restrict__ row_off, const int* __restrict__ deg,
    const float* __restrict__ deg_inv, const int* __restrict__ csr_src,
    unsigned short* __restrict__ outH) {
    const int wave = threadIdx.x >> 6;
    const int lane = threadIdx.x & 63;
    const int g = lane >> 3;        // node slot 0..7 within wave
    const int l = lane & 7;         // feature slice within node
    const int n = (blockIdx.x * 4 + wave) * 8 + g;
    const int start = row_off[n];
    const int d = deg[n];
    const float di = deg_inv[n];
    const int fo = l * 16;          // fp8 byte offset == bf16 element offset

    int dmax = d;
    dmax = max(dmax, __shfl_xor(dmax, 8, 64));
    dmax = max(dmax, __shfl_xor(dmax, 16, 64));
    dmax = max(dmax, __shfl_xor(dmax, 32, 64));

    const uint4 rv0 = *(const uint4*)&Rb[(size_t)n * HDIM + fo];
    const uint4 rv1 = *(const uint4*)&Rb[(size_t)n * HDIM + fo + 8];

    f32x2 acc2[8];
#pragma unroll
    for (int i = 0; i < 8; i++) acc2[i] = (f32x2){0.f, 0.f};

    int idxA = (l < d) ? csr_src[start + l] * HDIM : 0;
    int idxB = (8 + l < d) ? csr_src[start + 8 + l] * HDIM : 0;

    uint4 cur = {0u, 0u, 0u, 0u};
    {
        const int off0 = __shfl(idxA, g << 3, 64);        // full-exec shfl
        if (0 < d) cur = *(const uint4*)&Gq[(size_t)(unsigned)off0 + fo];
    }
#define ACC16(Cv)                                                        \
    acc2[0] += __builtin_amdgcn_cvt_pk_f32_fp8((int)(Cv).x, false);      \
    acc2[1] += __builtin_amdgcn_cvt_pk_f32_fp8((int)(Cv).x, true);       \
    acc2[2] += __builtin_amdgcn_cvt_pk_f32_fp8((int)(Cv).y, false);      \
    acc2[3] += __builtin_amdgcn_cvt_pk_f32_fp8((int)(Cv).y, true);       \
    acc2[4] += __builtin_amdgcn_cvt_pk_f32_fp8((int)(Cv).z, false);      \
    acc2[5] += __builtin_amdgcn_cvt_pk_f32_fp8((int)(Cv).z, true);       \
    acc2[6] += __builtin_amdgcn_cvt_pk_f32_fp8((int)(Cv).w, false);      \
    acc2[7] += __builtin_amdgcn_cvt_pk_f32_fp8((int)(Cv).w, true);

    for (int i = 1; i < dmax; i++) {
        const int sl = i & 7;
        if (sl == 0) {               // wave-uniform chunk rotation
            idxA = idxB;
            const int j = i + 8 + l;
            idxB = (j < d) ? csr_src[start + j] * HDIM : 0;
        }
        const int offn = __shfl(idxA, (g << 3) | sl, 64); // full-exec shfl
        uint4 nxt = {0u, 0u, 0u, 0u};
        if (i < d) nxt = *(const uint4*)&Gq[(size_t)(unsigned)offn + fo];
        ACC16(cur);                  // vmcnt(1): nxt stays in flight
        cur = nxt;
    }
    ACC16(cur);
#undef ACC16

    const float r[16] = {bf_lo(rv0.x), bf_hi(rv0.x), bf_lo(rv0.y), bf_hi(rv0.y),
                         bf_lo(rv0.z), bf_hi(rv0.z), bf_lo(rv0.w), bf_hi(rv0.w),
                         bf_lo(rv1.x), bf_hi(rv1.x), bf_lo(rv1.y), bf_hi(rv1.y),
                         bf_lo(rv1.z), bf_hi(rv1.z), bf_lo(rv1.w), bf_hi(rv1.w)};
    unsigned short o[16];
#pragma unroll
    for (int i = 0; i < 8; i++) {
        o[2 * i]     = f2bf(fmaxf(acc2[i].x * di + r[2 * i], 0.f));
        o[2 * i + 1] = f2bf(fmaxf(acc2[i].y * di + r[2 * i + 1], 0.f));
    }
    uint4 p0, p1;
    p0.x = (unsigned int)o[0] | ((unsigned int)o[1] << 16);
    p0.y = (unsigned int)o[2] | ((unsigned int)o[3] << 16);
    p0.z = (unsigned int)o[4] | ((unsigned int)o[5] << 16);
    p0.w = (unsigned int)o[6] | ((unsigned int)o[7] << 16);
    p1.x = (unsigned int)o[8] | ((unsigned int)o[9] << 16);
    p1.y = (unsigned int)o[10] | ((unsigned int)o[11] << 16);
    p1.z = (unsigned int)o[12] | ((unsigned int)o[13] << 16);
    p1.w = (unsigned int)o[14] | ((unsigned int)o[15] << 16);
    *(uint4*)&outH[(size_t)n * HDIM + fo] = p0;
    *(uint4*)&outH[(size_t)n * HDIM + fo + 8] = p1;
}

// ---------------- layer-2 dual GEMM (bf16 in, Gq fp8 + Rb bf16 out) -------
// Triple-buffered, counted vmcnt(1), stride GB2 (more TLP, shorter loop).

__global__ __launch_bounds__(256) void k_gemm2(
    const unsigned short* __restrict__ Ab, const unsigned short* __restrict__ W,
    const float* __restrict__ bias,
    unsigned char* __restrict__ Gq, unsigned short* __restrict__ Rb) {
    __shared__ __align__(16) unsigned char smem[3 * 4096 + 1024];
    float* bias_l = (float*)(smem + 3 * 4096);

    const int tix  = threadIdx.x;
    const int wave = tix >> 6;
    const int lane = tix & 63;
    const int m16  = lane & 15;
    const int quad = lane >> 4;
    const int u0   = wave * 4;
    const bool isG = (wave < 2);
    const int xk   = m16 & 7;

    bfrag wf[4][KCH];
#pragma unroll
    for (int u = 0; u < 4; u++) {
        const int j = (u0 + u) * 16 + m16;
#pragma unroll
        for (int c = 0; c < KCH; c++)
            wf[u][c] = *(const bfrag*)&W[(size_t)j * HDIM + c * 32 + quad * 8];
    }
    bias_l[tix] = bias[tix];

    const int sw = (tix ^ ((tix >> 4) & 7)) << 4;
    const int ldsoff = wave << 10;

    int tile = blockIdx.x;
    {
        const unsigned char* g = (const unsigned char*)Ab + (size_t)tile * 4096;
        gload_lds16(g + sw, smem + ldsoff);
    }
    asm volatile("s_waitcnt lgkmcnt(0)" ::: "memory");

    int b = 0;
    for (; tile < NTILES; tile += GB2) {
        const int tn = tile + GB2;
        if (tn < NTILES) {
            const unsigned char* g = (const unsigned char*)Ab + (size_t)tn * 4096;
            gload_lds16(g + sw, smem + (b == 2 ? 0 : b + 1) * 4096 + ldsoff);
        }
        asm volatile("s_waitcnt vmcnt(1)" ::: "memory");
        __builtin_amdgcn_s_barrier();
        __builtin_amdgcn_sched_barrier(0);

        const unsigned char* B = smem + b * 4096;
        bfrag hf[KCH];
#pragma unroll
        for (int c = 0; c < KCH; c++) {
            const int s = m16 * 16 + c * 4 + quad;
            hf[c] = *(const bfrag*)(B + ((s ^ xk) << 4));
        }

        const int node = tile * 16 + m16;
#pragma unroll
        for (int u = 0; u < 4; u++) {
            ffrag acc = {0.f, 0.f, 0.f, 0.f};
#pragma unroll
            for (int c = 0; c < KCH; c++)
                acc = __builtin_amdgcn_mfma_f32_16x16x32_bf16(wf[u][c], hf[c], acc, 0, 0, 0);
            const int jj0 = (u0 + u) * 16 + quad * 4;
            const float4 b0 = *(const float4*)&bias_l[jj0];
            float v[4] = {acc[0] + b0.x, acc[1] + b0.y, acc[2] + b0.z, acc[3] + b0.w};
            if (isG) {
                int pk = __builtin_amdgcn_cvt_pk_fp8_f32(v[0], v[1], 0, false);
                pk = __builtin_amdgcn_cvt_pk_fp8_f32(v[2], v[3], pk, true);
                *(unsigned int*)&Gq[(size_t)node * HDIM + (u0 + u) * 16 + quad * 4] =
                    (unsigned int)pk;
            } else {
                unsigned short o[4];
#pragma unroll
                for (int r = 0; r < 4; r++) o[r] = f2bf(v[r]);
                uint2 p = {(unsigned int)o[0] | ((unsigned int)o[1] << 16),
                           (unsigned int)o[2] | ((unsigned int)o[3] << 16)};
                *(uint2*)&Rb[(size_t)node * HDIM + (u0 + u - 8) * 16 + quad * 4] = p;
            }
        }
        b = (b == 2 ? 0 : b + 1);
    }
}

// ---------------- logits GEMM, j-major output ----------------

__global__ __launch_bounds__(256) void k_gemm_logits(
    const unsigned short* __restrict__ A, const unsigned short* __restrict__ W,
    const float* __restrict__ bias, float* __restrict__ out) {
    __shared__ __align__(16) unsigned char smem[3 * 4096];
    const int tix  = threadIdx.x;
    const int wave = tix >> 6;
    const int lane = tix & 63;
    const int m16  = lane & 15;
    const int quad = lane >> 4;
    const int u0   = wave * 2;
    const int xk   = m16 & 7;

    bfrag wf[2][KCH];
    float bsj[2];
#pragma unroll
    for (int u = 0; u < 2; u++) {
        const int unit = u0 + u;
        const int j = (unit < 7 ? unit : 0) * 16 + m16;
#pragma unroll
        for (int c = 0; c < KCH; c++)
            wf[u][c] = *(const bfrag*)&W[(size_t)j * HDIM + c * 32 + quad * 8];
        bsj[u] = bias[j];
    }

    const int sw2 = (tix ^ ((tix >> 4) & 7)) << 4;
    const int ldsoff = wave << 10;

    int tile = blockIdx.x;
    {
        const unsigned char* g = (const unsigned char*)A + (size_t)tile * 4096;
        gload_lds16(g + sw2, smem + ldsoff);
    }

    int b = 0;
    for (; tile < NTILES; tile += GB2) {
        const int tn = tile + GB2;
        if (tn < NTILES) {
            const unsigned char* g = (const unsigned char*)A + (size_t)tn * 4096;
            gload_lds16(g + sw2, smem + (b == 2 ? 0 : b + 1) * 4096 + ldsoff);
        }
        asm volatile("s_waitcnt vmcnt(1)" ::: "memory");
        __builtin_amdgcn_s_barrier();
        __builtin_amdgcn_sched_barrier(0);

        const unsigned char* B = smem + b * 4096;
        bfrag hf[KCH];
#pragma unroll
        for (int c = 0; c < KCH; c++) {
            const int s = m16 * 16 + c * 4 + quad;
            hf[c] = *(const bfrag*)(B + ((s ^ xk) << 4));
        }

#pragma unroll
        for (int u = 0; u < 2; u++) {
            const int unit = u0 + u;
            if (unit >= 7) break;
            ffrag acc = {0.f, 0.f, 0.f, 0.f};
#pragma unroll
            for (int c = 0; c < KCH; c++)
                acc = __builtin_amdgcn_mfma_f32_16x16x32_bf16(hf[c], wf[u][c], acc, 0, 0, 0);
            const int j = unit * 16 + m16;
            if (j < NUM_CARDS) {
#pragma unroll
                for (int r = 0; r < 4; r++) {
                    const int node = tile * 16 + quad * 4 + r;
                    out[(size_t)node * NUM_CARDS + j] = acc[r] + bsj[u];
                }
            }
        }
        b = (b == 2 ? 0 : b + 1);
    }
}

// ---------------- launch ----------------

static inline size_t align_up(size_t x, size_t a) { return (x + a - 1) & ~(a - 1); }

extern "C" void kernel_launch(void* const* d_in, const int* in_sizes, int n_in,
                              void* d_out, int out_size, void* d_ws, size_t ws_size,
                              hipStream_t stream) {
    const float* x   = (const float*)d_in[0];
    const float* Wl1 = (const float*)d_in[1];
    const float* bl1 = (const float*)d_in[2];
    const float* Wr1 = (const float*)d_in[3];
    const float* br1 = (const float*)d_in[4];
    const float* Wl2 = (const float*)d_in[5];
    const float* bl2 = (const float*)d_in[6];
    const float* Wr2 = (const float*)d_in[7];
    const float* br2 = (const float*)d_in[8];
    const float* Wo  = (const float*)d_in[9];
    const float* bo  = (const float*)d_in[10];
    const int* edge  = (const int*)d_in[11];
    const int* cards = (const int*)d_in[12];
    float* logits = (float*)d_out;

    const int* e_src = edge;
    const int* e_dst = edge + N_EDGES;

    char* w = (char*)d_ws;
    size_t off = 0;
    int* bucket_cursor = (int*)(w + off); off = align_up(off + 256 * 4, 512);
    unsigned int* part = (unsigned int*)(w + off); off = align_up(off + (size_t)NB * MAXB * 4, 512);
    int* row_off = (int*)(w + off); off = align_up(off + N_NODES * 4, 512);
    int* deg_i   = (int*)(w + off); off = align_up(off + N_NODES * 4, 512);
    float* dinv  = (float*)(w + off); off = align_up(off + N_NODES * 4, 512);
    int* csr_src = (int*)(w + off); off = align_up(off + (size_t)NB * MAXB * 4, 512);
    unsigned char*  Gq   = (unsigned char*)(w + off);  off = align_up(off + (size_t)N_NODES * HDIM, 512);
    unsigned short* Rb   = (unsigned short*)(w + off); off = align_up(off + (size_t)N_NODES * HDIM * 2, 512);
    unsigned short* bufH = (unsigned short*)(w + off); off = align_up(off + (size_t)N_NODES * HDIM * 2, 512);
    unsigned short* W1   = (unsigned short*)(w + off); off = align_up(off + 256 * HDIM * 2, 512);
    unsigned short* W2   = (unsigned short*)(w + off); off = align_up(off + 256 * HDIM * 2, 512);
    unsigned short* Wob  = (unsigned short*)(w + off); off = align_up(off + 112 * HDIM * 2, 512);
    float* bias1  = (float*)(w + off); off = align_up(off + 256 * 4, 512);
    float* bias2  = (float*)(w + off); off = align_up(off + 256 * 4, 512);
    float* biaso  = (float*)(w + off); off = align_up(off + 112 * 4, 512);
    float* wcard1 = (float*)(w + off); off = align_up(off + 256 * 4, 512);
    (void)ws_size; (void)n_in; (void)in_sizes; (void)out_size;

    hipMemsetAsync(bucket_cursor, 0, 256 * 4, stream);
    k_prep_w<<<256, 128, 0, stream>>>(Wl1, Wr1, bl1, br1, Wl2, Wr2, bl2, br2, Wo, bo,
                                      W1, W2, Wob, bias1, bias2, biaso, wcard1);

    // K1: edge partition || gemm1 first half
    k_part_gemm1<<<PBLK + GB1, 256, 0, stream>>>(
        e_src, e_dst, bucket_cursor, part,
        x, cards, W1, bias1, wcard1, Gq, Rb);
    // K2: bucket CSR finalize || gemm1 second half
    k_bucket_gemm1<<<NB + GB1, 256, 0, stream>>>(
        part, bucket_cursor, row_off, deg_i, dinv, csr_src,
        x, cards, W1, bias1, wcard1, Gq, Rb);

    // layer 1 aggregate
    k_agg<<<N_NODES / 32, 256, 0, stream>>>(Gq, Rb, row_off, deg_i, dinv, csr_src, bufH);
    // layer 2 GEMM
    k_gemm2<<<GB2, 256, 0, stream>>>(bufH, W2, bias2, Gq, Rb);
    // layer 2 aggregate
    k_agg<<<N_NODES / 32, 256, 0, stream>>>(Gq, Rb, row_off, deg_i, dinv, csr_src, bufH);
    // output logits
    k_gemm_logits<<<GB2, 256, 0, stream>>>(bufH, Wob, biaso, logits);
}